// Round 5
// baseline (167.386 us; speedup 1.0000x reference)
//
#include <hip/hip_runtime.h>
#include <hip/hip_bf16.h>
#include <stdint.h>

// MSDeformableAttention3D fused: bs=1, nq=40000=1250*32, embed=256, H=8, L=4, P=4,
// 16 value rows (14 cells used: HW sums 2+4+6+2), d=32.
// Block = 32 queries, 256 threads (4 waves) -> 1250 blocks; LDS 23040 B ->
// up to 7 blocks/CU (launch_bounds caps VGPR for 6).
// spatial_shapes static: (h,w) = (1,2),(2,2),(2,3),(1,2).
//
// LDS (time-multiplexed):
//   [0,23040):  GEMM sA[32][40] + sB[256][40] bf16          (phase 2)
//   [0,16384):  sOff [32][256] bf16, XOR-swizzled            (phase 3-4a)
//   [0,12288):  wsFrag [256][48B] bf16 A-fragments           (phase 4b-5)
//
// R4 bug fixed here: B staging must write 32 shorts/row (BK=32); R4 only
// staged 16 -> garbage in the lk>=16 fragments. Now pb[4] covers the row.

typedef __attribute__((ext_vector_type(8))) short short8;
typedef __attribute__((ext_vector_type(4))) float float4_;

#define LDSTR 40
#define SB_OFF 2560          // sA = 32*40*2 bytes
#define SMEM_BYTES 23040     // + sB = 256*40*2

static __device__ __forceinline__ uint16_t f2bf(float f) {
    union { float f; uint32_t u; } a; a.f = f;
    uint32_t r = a.u + 0x7fffu + ((a.u >> 16) & 1u);   // RNE
    return (uint16_t)(r >> 16);
}
static __device__ __forceinline__ float bf2f(uint16_t b) {
    union { uint32_t u; float f; } a; a.u = ((uint32_t)b) << 16;
    return a.f;
}

// outer-product scatter into compile-time bins; OOB corners match no cell.
template <int H_, int W_, int ST_>
static __device__ __forceinline__ void scatter(float* ws, float a, float x, float y) {
    float x0f = floorf(x), y0f = floorf(y);
    float fx = x - x0f, fy = y - y0f;
    int ix0 = (int)x0f, iy0 = (int)y0f;
    float xc[W_], yc[H_];
#pragma unroll
    for (int cx = 0; cx < W_; ++cx)
        xc[cx] = (ix0 == cx) ? (1.f - fx) : ((ix0 + 1 == cx) ? fx : 0.f);
#pragma unroll
    for (int cy = 0; cy < H_; ++cy)
        yc[cy] = ((iy0 == cy) ? (1.f - fy) : ((iy0 + 1 == cy) ? fy : 0.f)) * a;
#pragma unroll
    for (int cy = 0; cy < H_; ++cy)
#pragma unroll
        for (int cx = 0; cx < W_; ++cx)
            ws[ST_ + cy * W_ + cx] += xc[cx] * yc[cy];
}

// ---------------- W_so^T as bf16 (256x256) ----------------
__global__ __launch_bounds__(256) void k_transpose(const float* __restrict__ W,
                                                   uint16_t* __restrict__ WTb) {
    int n = blockIdx.x, k = threadIdx.x;
    WTb[n * 256 + k] = f2bf(W[k * 256 + n]);
}

// ---------------- fused kernel ----------------
__global__ __launch_bounds__(256, 6) void k_fused(const float* __restrict__ q,
                                                  const float* __restrict__ key,
                                                  const float* __restrict__ value,
                                                  const float* __restrict__ refp,
                                                  const uint16_t* __restrict__ WTb,
                                                  const float* __restrict__ bso,
                                                  float* __restrict__ out) {
    __shared__ __align__(16) char smem[SMEM_BYTES];
    short* sA = (short*)smem;
    short* sB = (short*)(smem + SB_OFF);

    int t = threadIdx.x;
    int w = t >> 6, l = t & 63;
    int g = l >> 4, lrow = l & 15, lk = g * 8;
    int qbase = blockIdx.x * 32;
    int h2 = t >> 5, ql = t & 31;      // sampling mapping: thread <-> (head, query)
    int qa = qbase + ql;

    // ---- phase 2: off-GEMM 32x256, bf16 MFMA, reg-double-buffered staging ----
    int ar = t >> 3, ak = t & 7;       // A staging: row 0..31, float4-col 0..7
    float4_ acc[2][4];
#pragma unroll
    for (int i = 0; i < 2; ++i)
#pragma unroll
        for (int j = 0; j < 4; ++j) acc[i][j] = (float4_)0.f;

    float4_ pa = *(const float4_*)(q + (size_t)(qbase + ar) * 256 + ak * 4);
    short8 pb[4];
#pragma unroll
    for (int j = 0; j < 4; ++j)
        pb[j] = *(const short8*)(WTb + t * 256 + j * 8);

    for (int ks = 0; ks < 8; ++ks) {
        __syncthreads();
        {   // LDS writes from prefetch regs (full 32-short rows)
            uint32_t p0 = (uint32_t)f2bf(pa.x) | ((uint32_t)f2bf(pa.y) << 16);
            uint32_t p1 = (uint32_t)f2bf(pa.z) | ((uint32_t)f2bf(pa.w) << 16);
            uint32_t* dst = (uint32_t*)&sA[ar * LDSTR + ak * 4];
            dst[0] = p0; dst[1] = p1;
#pragma unroll
            for (int j = 0; j < 4; ++j)
                *(short8*)&sB[t * LDSTR + j * 8] = pb[j];
        }
        if (ks < 7) {   // issue next-chunk loads; land during MFMA/barrier
            pa = *(const float4_*)(q + (size_t)(qbase + ar) * 256 + (ks + 1) * 32 + ak * 4);
#pragma unroll
            for (int j = 0; j < 4; ++j)
                pb[j] = *(const short8*)(WTb + t * 256 + (ks + 1) * 32 + j * 8);
        }
        __syncthreads();
        short8 af[2], bf[4];
#pragma unroll
        for (int mi = 0; mi < 2; ++mi)
            af[mi] = *(const short8*)&sA[(mi * 16 + lrow) * LDSTR + lk];
#pragma unroll
        for (int ni = 0; ni < 4; ++ni)
            bf[ni] = *(const short8*)&sB[(w * 64 + ni * 16 + lrow) * LDSTR + lk];
#pragma unroll
        for (int mi = 0; mi < 2; ++mi)
#pragma unroll
            for (int ni = 0; ni < 4; ++ni)
                acc[mi][ni] = __builtin_amdgcn_mfma_f32_16x16x32_bf16(
                    af[mi], bf[ni], acc[mi][ni], 0, 0, 0);
    }
    __syncthreads();   // frag reads done before sOff overwrites sA/sB

    // ---- phase 3a: epilogue -> sOff (swizzled [32][256] bf16) ----
#pragma unroll
    for (int mi = 0; mi < 2; ++mi)
#pragma unroll
        for (int ni = 0; ni < 4; ++ni) {
            int col = w * 64 + ni * 16 + lrow;
            float b = bso[col];
            int qrow = mi * 16 + g * 4;
#pragma unroll
            for (int r = 0; r < 4; ++r) {
                int row = qrow + r;
                *(uint16_t*)(smem + row * 512 + ((col * 2) ^ ((row & 7) << 4))) =
                    f2bf(acc[mi][ni][r] + b);
            }
        }

    // ---- phase 3b: fp32 scores (thread = (h2, ql)) + in-thread softmax ----
    // two half-d passes to keep register peak low
    float sc[16];
#pragma unroll
    for (int kk = 0; kk < 16; ++kk) sc[kk] = 0.f;
#pragma unroll
    for (int half = 0; half < 2; ++half) {
        const float4_* qp = (const float4_*)(q + (size_t)qa * 256 + h2 * 32 + half * 16);
        float4_ qv[4];
#pragma unroll
        for (int j = 0; j < 4; ++j) qv[j] = qp[j];
#pragma unroll
        for (int kk = 0; kk < 16; ++kk) {
            const float4_* kp = (const float4_*)(key + kk * 256 + h2 * 32 + half * 16);
            float a = 0.f;
#pragma unroll
            for (int j = 0; j < 4; ++j) {
                float4_ kv = kp[j];
                a += qv[j].x * kv.x + qv[j].y * kv.y + qv[j].z * kv.z + qv[j].w * kv.w;
            }
            sc[kk] += a;
        }
    }
    {
        float m = sc[0];
#pragma unroll
        for (int kk = 1; kk < 16; ++kk) m = fmaxf(m, sc[kk]);
        float s = 0.f;
#pragma unroll
        for (int kk = 0; kk < 16; ++kk) { sc[kk] = __expf(sc[kk] - m); s += sc[kk]; }
        float inv = 1.f / s;
#pragma unroll
        for (int kk = 0; kk < 16; ++kk) sc[kk] *= inv;
    }
    __syncthreads();

    // ---- phase 4a: read own offsets, sample into register bins ----
    union OvU { short8 v; short s[8]; } ov[4];
#pragma unroll
    for (int i = 0; i < 4; ++i)
        ov[i].v = *(const short8*)(smem + ql * 512 + ((h2 * 64 + i * 16) ^ ((ql & 7) << 4)));

    float4_ r01 = *(const float4_*)(refp + (size_t)qa * 8);
    float4_ r23 = *(const float4_*)(refp + (size_t)qa * 8 + 4);
    float rx[4] = {r01.x, r01.z, r23.x, r23.z};
    float ry[4] = {r01.y, r01.w, r23.y, r23.w};

    float ws[14];
#pragma unroll
    for (int j = 0; j < 14; ++j) ws[j] = 0.f;

    // norm by (W,H)[pp]: W={2,2,3,2}, H={1,2,2,1}; sample grid by lev.
#define SAMPLE_LP(LP, PP, GH, GW, ST, NW, NH)                                     \
    {                                                                             \
        float ox = bf2f((uint16_t)ov[(2 * (LP)) >> 3].s[(2 * (LP)) & 7]);         \
        float oy = bf2f((uint16_t)ov[(2 * (LP) + 1) >> 3].s[(2 * (LP) + 1) & 7]); \
        float x = (rx[PP] + ox * (NW)) * (float)(GW)-0.5f;                        \
        float y = (ry[PP] + oy * (NH)) * (float)(GH)-0.5f;                        \
        scatter<GH, GW, ST>(ws, sc[LP], x, y);                                    \
    }
    SAMPLE_LP(0, 0, 1, 2, 0, 0.5f, 1.0f)
    SAMPLE_LP(1, 1, 1, 2, 0, 0.5f, 0.5f)
    SAMPLE_LP(2, 2, 1, 2, 0, (1.f / 3.f), 0.5f)
    SAMPLE_LP(3, 3, 1, 2, 0, 0.5f, 1.0f)
    SAMPLE_LP(4, 0, 2, 2, 2, 0.5f, 1.0f)
    SAMPLE_LP(5, 1, 2, 2, 2, 0.5f, 0.5f)
    SAMPLE_LP(6, 2, 2, 2, 2, (1.f / 3.f), 0.5f)
    SAMPLE_LP(7, 3, 2, 2, 2, 0.5f, 1.0f)
    SAMPLE_LP(8, 0, 2, 3, 6, 0.5f, 1.0f)
    SAMPLE_LP(9, 1, 2, 3, 6, 0.5f, 0.5f)
    SAMPLE_LP(10, 2, 2, 3, 6, (1.f / 3.f), 0.5f)
    SAMPLE_LP(11, 3, 2, 3, 6, 0.5f, 1.0f)
    SAMPLE_LP(12, 0, 1, 2, 12, 0.5f, 1.0f)
    SAMPLE_LP(13, 1, 1, 2, 12, 0.5f, 0.5f)
    SAMPLE_LP(14, 2, 1, 2, 12, (1.f / 3.f), 0.5f)
    SAMPLE_LP(15, 3, 1, 2, 12, 0.5f, 1.0f)
#undef SAMPLE_LP

    __syncthreads();   // everyone done reading sOff

    // ---- phase 4b: pack ws -> wsFrag [256][48B] (row = t = h2*32+ql) ----
    {
        union PkU { uint32_t u[8]; short8 v2[2]; } pk;
#pragma unroll
        for (int j = 0; j < 7; ++j)
            pk.u[j] = (uint32_t)f2bf(ws[2 * j]) | ((uint32_t)f2bf(ws[2 * j + 1]) << 16);
        pk.u[7] = 0;
        *(short8*)(smem + t * 48)      = pk.v2[0];
        *(short8*)(smem + t * 48 + 16) = pk.v2[1];
    }
    __syncthreads();

    // ---- phase 5: out = wsum @ value; wave w serves heads {2w, 2w+1} ----
    {
        union ZU { uint32_t u[4]; short8 v; } az;
        az.u[0] = 0; az.u[1] = 0; az.u[2] = 0; az.u[3] = 0;
#pragma unroll
        for (int hh = 0; hh < 2; ++hh) {
            int h = 2 * w + hh;
            union VbU { short8 v; uint16_t u[8]; } vb[2];
#pragma unroll
            for (int nt = 0; nt < 2; ++nt) {
                if (g < 2) {
                    int col = h * 32 + nt * 16 + lrow;
#pragma unroll
                    for (int j = 0; j < 8; ++j)
                        vb[nt].u[j] = f2bf(value[(g * 8 + j) * 256 + col]);
                } else {
                    vb[nt].v = az.v;
                }
            }
            float4_ acc2[2][2];
#pragma unroll
            for (int i = 0; i < 2; ++i)
#pragma unroll
                for (int j = 0; j < 2; ++j) acc2[i][j] = (float4_)0.f;
#pragma unroll
            for (int mt = 0; mt < 2; ++mt) {
                short8 af = (g < 2)
                    ? *(const short8*)(smem + (h * 32 + mt * 16 + lrow) * 48 + g * 16)
                    : az.v;
#pragma unroll
                for (int nt = 0; nt < 2; ++nt)
                    acc2[mt][nt] = __builtin_amdgcn_mfma_f32_16x16x32_bf16(
                        af, vb[nt].v, acc2[mt][nt], 0, 0, 0);
            }
#pragma unroll
            for (int mt = 0; mt < 2; ++mt)
#pragma unroll
                for (int nt = 0; nt < 2; ++nt)
#pragma unroll
                    for (int r = 0; r < 4; ++r)
                        out[(size_t)(qbase + mt * 16 + g * 4 + r) * 256
                            + h * 32 + nt * 16 + lrow] = acc2[mt][nt][r];
        }
    }
}

extern "C" void kernel_launch(void* const* d_in, const int* in_sizes, int n_in,
                              void* d_out, int out_size, void* d_ws, size_t ws_size,
                              hipStream_t stream) {
    (void)in_sizes; (void)n_in; (void)out_size; (void)ws_size;
    const float* query = (const float*)d_in[0];
    const float* key   = (const float*)d_in[1];
    const float* value = (const float*)d_in[2];
    const float* refp  = (const float*)d_in[3];
    const float* Wso   = (const float*)d_in[5];
    const float* bso   = (const float*)d_in[6];
    uint16_t* WTb = (uint16_t*)d_ws;

    hipLaunchKernelGGL(k_transpose, dim3(256), dim3(256), 0, stream, Wso, WTb);
    hipLaunchKernelGGL(k_fused, dim3(1250), dim3(256), 0, stream,
                       query, key, value, refp, WTb, bso, (float*)d_out);
}

// Round 6
// 107.483 us; speedup vs baseline: 1.5573x; 1.5573x over previous
//
#include <hip/hip_runtime.h>
#include <hip/hip_bf16.h>
#include <stdint.h>

// MSDeformableAttention3D fused: bs=1, nq=40000=1250*32, embed=256, H=8, L=4, P=4,
// 16 value rows (14 cells used: HW sums 2+4+6+2), d=32.
// Block = 32 queries, 256 threads (4 waves) -> 1250 blocks; LDS 23040 B.
// spatial_shapes static: (h,w) = (1,2),(2,2),(2,3),(1,2).
//
// R5 lesson: __launch_bounds__(256,6) capped VGPR at 40 < ~100 live regs ->
// massive scratch spill (WRITE_SIZE 268MB, occupancy 0.8%). Now (256,4):
// cap 128, expect ~4 blocks/CU (16 waves, 50%).
//
// LDS (time-multiplexed):
//   [0,23040):  GEMM sA[32][40] + sB[256][40] bf16          (phase 2)
//   [0,16384):  sOff [32][256] bf16, XOR-swizzled            (phase 3-4a)
//   [0,12288):  wsFrag [256][48B] bf16 A-fragments           (phase 4b-5)

typedef __attribute__((ext_vector_type(8))) short short8;
typedef __attribute__((ext_vector_type(4))) float float4_;

#define LDSTR 40
#define SB_OFF 2560          // sA = 32*40*2 bytes
#define SMEM_BYTES 23040     // + sB = 256*40*2

static __device__ __forceinline__ uint16_t f2bf(float f) {
    union { float f; uint32_t u; } a; a.f = f;
    uint32_t r = a.u + 0x7fffu + ((a.u >> 16) & 1u);   // RNE
    return (uint16_t)(r >> 16);
}
static __device__ __forceinline__ float bf2f(uint16_t b) {
    union { uint32_t u; float f; } a; a.u = ((uint32_t)b) << 16;
    return a.f;
}

// outer-product scatter into compile-time bins; OOB corners match no cell.
template <int H_, int W_, int ST_>
static __device__ __forceinline__ void scatter(float* ws, float a, float x, float y) {
    float x0f = floorf(x), y0f = floorf(y);
    float fx = x - x0f, fy = y - y0f;
    int ix0 = (int)x0f, iy0 = (int)y0f;
    float xc[W_], yc[H_];
#pragma unroll
    for (int cx = 0; cx < W_; ++cx)
        xc[cx] = (ix0 == cx) ? (1.f - fx) : ((ix0 + 1 == cx) ? fx : 0.f);
#pragma unroll
    for (int cy = 0; cy < H_; ++cy)
        yc[cy] = ((iy0 == cy) ? (1.f - fy) : ((iy0 + 1 == cy) ? fy : 0.f)) * a;
#pragma unroll
    for (int cy = 0; cy < H_; ++cy)
#pragma unroll
        for (int cx = 0; cx < W_; ++cx)
            ws[ST_ + cy * W_ + cx] += xc[cx] * yc[cy];
}

// ---------------- W_so^T as bf16 (256x256) ----------------
__global__ __launch_bounds__(256) void k_transpose(const float* __restrict__ W,
                                                   uint16_t* __restrict__ WTb) {
    int n = blockIdx.x, k = threadIdx.x;
    WTb[n * 256 + k] = f2bf(W[k * 256 + n]);
}

// ---------------- fused kernel ----------------
__global__ __launch_bounds__(256, 4) void k_fused(const float* __restrict__ q,
                                                  const float* __restrict__ key,
                                                  const float* __restrict__ value,
                                                  const float* __restrict__ refp,
                                                  const uint16_t* __restrict__ WTb,
                                                  const float* __restrict__ bso,
                                                  float* __restrict__ out) {
    __shared__ __align__(16) char smem[SMEM_BYTES];
    short* sA = (short*)smem;
    short* sB = (short*)(smem + SB_OFF);

    int t = threadIdx.x;
    int w = t >> 6, l = t & 63;
    int g = l >> 4, lrow = l & 15, lk = g * 8;
    int qbase = blockIdx.x * 32;
    int h2 = t >> 5, ql = t & 31;      // sampling mapping: thread <-> (head, query)
    int qa = qbase + ql;

    // ---- phase 2: off-GEMM 32x256, bf16 MFMA, reg-double-buffered staging ----
    int ar = t >> 3, ak = t & 7;       // A staging: row 0..31, float4-col 0..7
    float4_ acc[2][4];
#pragma unroll
    for (int i = 0; i < 2; ++i)
#pragma unroll
        for (int j = 0; j < 4; ++j) acc[i][j] = (float4_)0.f;

    float4_ pa = *(const float4_*)(q + (size_t)(qbase + ar) * 256 + ak * 4);
    short8 pb[4];
#pragma unroll
    for (int j = 0; j < 4; ++j)
        pb[j] = *(const short8*)(WTb + t * 256 + j * 8);

    for (int ks = 0; ks < 8; ++ks) {
        __syncthreads();
        {   // LDS writes from prefetch regs (full 32-short rows)
            uint32_t p0 = (uint32_t)f2bf(pa.x) | ((uint32_t)f2bf(pa.y) << 16);
            uint32_t p1 = (uint32_t)f2bf(pa.z) | ((uint32_t)f2bf(pa.w) << 16);
            uint32_t* dst = (uint32_t*)&sA[ar * LDSTR + ak * 4];
            dst[0] = p0; dst[1] = p1;
#pragma unroll
            for (int j = 0; j < 4; ++j)
                *(short8*)&sB[t * LDSTR + j * 8] = pb[j];
        }
        if (ks < 7) {   // issue next-chunk loads; land during MFMA/barrier
            pa = *(const float4_*)(q + (size_t)(qbase + ar) * 256 + (ks + 1) * 32 + ak * 4);
#pragma unroll
            for (int j = 0; j < 4; ++j)
                pb[j] = *(const short8*)(WTb + t * 256 + (ks + 1) * 32 + j * 8);
        }
        __syncthreads();
        short8 af[2], bf[4];
#pragma unroll
        for (int mi = 0; mi < 2; ++mi)
            af[mi] = *(const short8*)&sA[(mi * 16 + lrow) * LDSTR + lk];
#pragma unroll
        for (int ni = 0; ni < 4; ++ni)
            bf[ni] = *(const short8*)&sB[(w * 64 + ni * 16 + lrow) * LDSTR + lk];
#pragma unroll
        for (int mi = 0; mi < 2; ++mi)
#pragma unroll
            for (int ni = 0; ni < 4; ++ni)
                acc[mi][ni] = __builtin_amdgcn_mfma_f32_16x16x32_bf16(
                    af[mi], bf[ni], acc[mi][ni], 0, 0, 0);
    }
    __syncthreads();   // frag reads done before sOff overwrites sA/sB

    // ---- phase 3a: epilogue -> sOff (swizzled [32][256] bf16) ----
#pragma unroll
    for (int mi = 0; mi < 2; ++mi)
#pragma unroll
        for (int ni = 0; ni < 4; ++ni) {
            int col = w * 64 + ni * 16 + lrow;
            float b = bso[col];
            int qrow = mi * 16 + g * 4;
#pragma unroll
            for (int r = 0; r < 4; ++r) {
                int row = qrow + r;
                *(uint16_t*)(smem + row * 512 + ((col * 2) ^ ((row & 7) << 4))) =
                    f2bf(acc[mi][ni][r] + b);
            }
        }

    // ---- phase 3b: fp32 scores (thread = (h2, ql)) + in-thread softmax ----
    // two half-d passes to keep register peak low
    float sc[16];
#pragma unroll
    for (int kk = 0; kk < 16; ++kk) sc[kk] = 0.f;
#pragma unroll
    for (int half = 0; half < 2; ++half) {
        const float4_* qp = (const float4_*)(q + (size_t)qa * 256 + h2 * 32 + half * 16);
        float4_ qv[4];
#pragma unroll
        for (int j = 0; j < 4; ++j) qv[j] = qp[j];
#pragma unroll
        for (int kk = 0; kk < 16; ++kk) {
            const float4_* kp = (const float4_*)(key + kk * 256 + h2 * 32 + half * 16);
            float a = 0.f;
#pragma unroll
            for (int j = 0; j < 4; ++j) {
                float4_ kv = kp[j];
                a += qv[j].x * kv.x + qv[j].y * kv.y + qv[j].z * kv.z + qv[j].w * kv.w;
            }
            sc[kk] += a;
        }
    }
    {
        float m = sc[0];
#pragma unroll
        for (int kk = 1; kk < 16; ++kk) m = fmaxf(m, sc[kk]);
        float s = 0.f;
#pragma unroll
        for (int kk = 0; kk < 16; ++kk) { sc[kk] = __expf(sc[kk] - m); s += sc[kk]; }
        float inv = 1.f / s;
#pragma unroll
        for (int kk = 0; kk < 16; ++kk) sc[kk] *= inv;
    }
    __syncthreads();

    // ---- phase 4a: sample into register bins; offsets loaded per-level ----
    float4_ r01 = *(const float4_*)(refp + (size_t)qa * 8);
    float4_ r23 = *(const float4_*)(refp + (size_t)qa * 8 + 4);
    float rx[4] = {r01.x, r01.z, r23.x, r23.z};
    float ry[4] = {r01.y, r01.w, r23.y, r23.w};

    float ws[14];
#pragma unroll
    for (int j = 0; j < 14; ++j) ws[j] = 0.f;

    // norm by (W,H)[pp]: W={2,2,3,2}, H={1,2,2,1}; sample grid by lev.
    // Level lev's 4 points live in one short8 at sOff col h2*64+lev*16.
#define SAMPLE_PT(J, PP, GH, GW, ST, NW, NH)                                  \
    {                                                                         \
        float ox = bf2f((uint16_t)ovl.s[2 * (J)]);                            \
        float oy = bf2f((uint16_t)ovl.s[2 * (J) + 1]);                        \
        float x = (rx[PP] + ox * (NW)) * (float)(GW)-0.5f;                    \
        float y = (ry[PP] + oy * (NH)) * (float)(GH)-0.5f;                    \
        scatter<GH, GW, ST>(ws, sc[4 * LEV + (J)], x, y);                     \
    }
    {
        union OvU { short8 v; short s[8]; } ovl;
#define LEV 0
        ovl.v = *(const short8*)(smem + ql * 512 + ((h2 * 64 + LEV * 16) ^ ((ql & 7) << 4)));
        SAMPLE_PT(0, 0, 1, 2, 0, 0.5f, 1.0f)
        SAMPLE_PT(1, 1, 1, 2, 0, 0.5f, 0.5f)
        SAMPLE_PT(2, 2, 1, 2, 0, (1.f / 3.f), 0.5f)
        SAMPLE_PT(3, 3, 1, 2, 0, 0.5f, 1.0f)
#undef LEV
#define LEV 1
        ovl.v = *(const short8*)(smem + ql * 512 + ((h2 * 64 + LEV * 16) ^ ((ql & 7) << 4)));
        SAMPLE_PT(0, 0, 2, 2, 2, 0.5f, 1.0f)
        SAMPLE_PT(1, 1, 2, 2, 2, 0.5f, 0.5f)
        SAMPLE_PT(2, 2, 2, 2, 2, (1.f / 3.f), 0.5f)
        SAMPLE_PT(3, 3, 2, 2, 2, 0.5f, 1.0f)
#undef LEV
#define LEV 2
        ovl.v = *(const short8*)(smem + ql * 512 + ((h2 * 64 + LEV * 16) ^ ((ql & 7) << 4)));
        SAMPLE_PT(0, 0, 2, 3, 6, 0.5f, 1.0f)
        SAMPLE_PT(1, 1, 2, 3, 6, 0.5f, 0.5f)
        SAMPLE_PT(2, 2, 2, 3, 6, (1.f / 3.f), 0.5f)
        SAMPLE_PT(3, 3, 2, 3, 6, 0.5f, 1.0f)
#undef LEV
#define LEV 3
        ovl.v = *(const short8*)(smem + ql * 512 + ((h2 * 64 + LEV * 16) ^ ((ql & 7) << 4)));
        SAMPLE_PT(0, 0, 1, 2, 12, 0.5f, 1.0f)
        SAMPLE_PT(1, 1, 1, 2, 12, 0.5f, 0.5f)
        SAMPLE_PT(2, 2, 1, 2, 12, (1.f / 3.f), 0.5f)
        SAMPLE_PT(3, 3, 1, 2, 12, 0.5f, 1.0f)
#undef LEV
    }
#undef SAMPLE_PT

    __syncthreads();   // everyone done reading sOff

    // ---- phase 4b: pack ws -> wsFrag [256][48B] (row = t = h2*32+ql) ----
    {
        union PkU { uint32_t u[8]; short8 v2[2]; } pk;
#pragma unroll
        for (int j = 0; j < 7; ++j)
            pk.u[j] = (uint32_t)f2bf(ws[2 * j]) | ((uint32_t)f2bf(ws[2 * j + 1]) << 16);
        pk.u[7] = 0;
        *(short8*)(smem + t * 48)      = pk.v2[0];
        *(short8*)(smem + t * 48 + 16) = pk.v2[1];
    }
    __syncthreads();

    // ---- phase 5: out = wsum @ value; wave w serves heads {2w, 2w+1} ----
    {
        union ZU { uint32_t u[4]; short8 v; } az;
        az.u[0] = 0; az.u[1] = 0; az.u[2] = 0; az.u[3] = 0;
#pragma unroll
        for (int hh = 0; hh < 2; ++hh) {
            int h = 2 * w + hh;
            union VbU { short8 v; uint16_t u[8]; } vb[2];
#pragma unroll
            for (int nt = 0; nt < 2; ++nt) {
                if (g < 2) {
                    int col = h * 32 + nt * 16 + lrow;
#pragma unroll
                    for (int j = 0; j < 8; ++j)
                        vb[nt].u[j] = f2bf(value[(g * 8 + j) * 256 + col]);
                } else {
                    vb[nt].v = az.v;
                }
            }
            float4_ acc2[2][2];
#pragma unroll
            for (int i = 0; i < 2; ++i)
#pragma unroll
                for (int j = 0; j < 2; ++j) acc2[i][j] = (float4_)0.f;
#pragma unroll
            for (int mt = 0; mt < 2; ++mt) {
                short8 af = (g < 2)
                    ? *(const short8*)(smem + (h * 32 + mt * 16 + lrow) * 48 + g * 16)
                    : az.v;
#pragma unroll
                for (int nt = 0; nt < 2; ++nt)
                    acc2[mt][nt] = __builtin_amdgcn_mfma_f32_16x16x32_bf16(
                        af, vb[nt].v, acc2[mt][nt], 0, 0, 0);
            }
#pragma unroll
            for (int mt = 0; mt < 2; ++mt)
#pragma unroll
                for (int nt = 0; nt < 2; ++nt)
#pragma unroll
                    for (int r = 0; r < 4; ++r)
                        out[(size_t)(qbase + mt * 16 + g * 4 + r) * 256
                            + h * 32 + nt * 16 + lrow] = acc2[mt][nt][r];
        }
    }
}

extern "C" void kernel_launch(void* const* d_in, const int* in_sizes, int n_in,
                              void* d_out, int out_size, void* d_ws, size_t ws_size,
                              hipStream_t stream) {
    (void)in_sizes; (void)n_in; (void)out_size; (void)ws_size;
    const float* query = (const float*)d_in[0];
    const float* key   = (const float*)d_in[1];
    const float* value = (const float*)d_in[2];
    const float* refp  = (const float*)d_in[3];
    const float* Wso   = (const float*)d_in[5];
    const float* bso   = (const float*)d_in[6];
    uint16_t* WTb = (uint16_t*)d_ws;

    hipLaunchKernelGGL(k_transpose, dim3(256), dim3(256), 0, stream, Wso, WTb);
    hipLaunchKernelGGL(k_fused, dim3(1250), dim3(256), 0, stream,
                       query, key, value, refp, WTb, bso, (float*)d_out);
}

// Round 8
// 72.734 us; speedup vs baseline: 2.3014x; 1.4778x over previous
//
#include <hip/hip_runtime.h>
#include <hip/hip_bf16.h>
#include <stdint.h>

// MSDeformableAttention3D fused: bs=1, nq=40000=1250*32, embed=256, H=8, L=4, P=4,
// 16 value rows (14 cells used: HW sums 2+4+6+2), d=32.
// Block = 32 queries, 256 threads (4 waves) -> 1250 blocks; LDS 23040 B.
// spatial_shapes static: (h,w) = (1,2),(2,2),(2,3),(1,2).
//
// R8 = R6 exactly, minus the launch_bounds min-occupancy arg. Evidence:
// unconstrained allocator never spilled (R2: VGPR 128, R3: VGPR 52, both
// WRITE_SIZE == output); every constrained build spilled (R5: 268MB, R6:
// 150MB scratch). Expect ~4 blocks/CU via VGPR, zero scratch.
//
// LDS (time-multiplexed):
//   [0,23040):  GEMM sA[32][40] + sB[256][40] bf16          (phase 2)
//   [0,16384):  sOff [32][256] bf16, XOR-swizzled            (phase 3-4a)
//   [0,12288):  wsFrag [256][48B] bf16 A-fragments           (phase 4b-5)

typedef __attribute__((ext_vector_type(8))) short short8;
typedef __attribute__((ext_vector_type(4))) float float4_;

#define LDSTR 40
#define SB_OFF 2560          // sA = 32*40*2 bytes
#define SMEM_BYTES 23040     // + sB = 256*40*2

static __device__ __forceinline__ uint16_t f2bf(float f) {
    union { float f; uint32_t u; } a; a.f = f;
    uint32_t r = a.u + 0x7fffu + ((a.u >> 16) & 1u);   // RNE
    return (uint16_t)(r >> 16);
}
static __device__ __forceinline__ float bf2f(uint16_t b) {
    union { uint32_t u; float f; } a; a.u = ((uint32_t)b) << 16;
    return a.f;
}

// outer-product scatter into compile-time bins; OOB corners match no cell.
template <int H_, int W_, int ST_>
static __device__ __forceinline__ void scatter(float* ws, float a, float x, float y) {
    float x0f = floorf(x), y0f = floorf(y);
    float fx = x - x0f, fy = y - y0f;
    int ix0 = (int)x0f, iy0 = (int)y0f;
    float xc[W_], yc[H_];
#pragma unroll
    for (int cx = 0; cx < W_; ++cx)
        xc[cx] = (ix0 == cx) ? (1.f - fx) : ((ix0 + 1 == cx) ? fx : 0.f);
#pragma unroll
    for (int cy = 0; cy < H_; ++cy)
        yc[cy] = ((iy0 == cy) ? (1.f - fy) : ((iy0 + 1 == cy) ? fy : 0.f)) * a;
#pragma unroll
    for (int cy = 0; cy < H_; ++cy)
#pragma unroll
        for (int cx = 0; cx < W_; ++cx)
            ws[ST_ + cy * W_ + cx] += xc[cx] * yc[cy];
}

// ---------------- W_so^T as bf16 (256x256) ----------------
__global__ __launch_bounds__(256) void k_transpose(const float* __restrict__ W,
                                                   uint16_t* __restrict__ WTb) {
    int n = blockIdx.x, k = threadIdx.x;
    WTb[n * 256 + k] = f2bf(W[k * 256 + n]);
}

// ---------------- fused kernel ----------------
__global__ __launch_bounds__(256) void k_fused(const float* __restrict__ q,
                                               const float* __restrict__ key,
                                               const float* __restrict__ value,
                                               const float* __restrict__ refp,
                                               const uint16_t* __restrict__ WTb,
                                               const float* __restrict__ bso,
                                               float* __restrict__ out) {
    __shared__ __align__(16) char smem[SMEM_BYTES];
    short* sA = (short*)smem;
    short* sB = (short*)(smem + SB_OFF);

    int t = threadIdx.x;
    int w = t >> 6, l = t & 63;
    int g = l >> 4, lrow = l & 15, lk = g * 8;
    int qbase = blockIdx.x * 32;
    int h2 = t >> 5, ql = t & 31;      // sampling mapping: thread <-> (head, query)
    int qa = qbase + ql;

    // ---- phase 2: off-GEMM 32x256, bf16 MFMA, reg-double-buffered staging ----
    int ar = t >> 3, ak = t & 7;       // A staging: row 0..31, float4-col 0..7
    float4_ acc[2][4];
#pragma unroll
    for (int i = 0; i < 2; ++i)
#pragma unroll
        for (int j = 0; j < 4; ++j) acc[i][j] = (float4_)0.f;

    float4_ pa = *(const float4_*)(q + (size_t)(qbase + ar) * 256 + ak * 4);
    short8 pb[4];
#pragma unroll
    for (int j = 0; j < 4; ++j)
        pb[j] = *(const short8*)(WTb + t * 256 + j * 8);

    for (int ks = 0; ks < 8; ++ks) {
        __syncthreads();
        {   // LDS writes from prefetch regs (full 32-short rows)
            uint32_t p0 = (uint32_t)f2bf(pa.x) | ((uint32_t)f2bf(pa.y) << 16);
            uint32_t p1 = (uint32_t)f2bf(pa.z) | ((uint32_t)f2bf(pa.w) << 16);
            uint32_t* dst = (uint32_t*)&sA[ar * LDSTR + ak * 4];
            dst[0] = p0; dst[1] = p1;
#pragma unroll
            for (int j = 0; j < 4; ++j)
                *(short8*)&sB[t * LDSTR + j * 8] = pb[j];
        }
        if (ks < 7) {   // issue next-chunk loads; land during MFMA/barrier
            pa = *(const float4_*)(q + (size_t)(qbase + ar) * 256 + (ks + 1) * 32 + ak * 4);
#pragma unroll
            for (int j = 0; j < 4; ++j)
                pb[j] = *(const short8*)(WTb + t * 256 + (ks + 1) * 32 + j * 8);
        }
        __syncthreads();
        short8 af[2], bf[4];
#pragma unroll
        for (int mi = 0; mi < 2; ++mi)
            af[mi] = *(const short8*)&sA[(mi * 16 + lrow) * LDSTR + lk];
#pragma unroll
        for (int ni = 0; ni < 4; ++ni)
            bf[ni] = *(const short8*)&sB[(w * 64 + ni * 16 + lrow) * LDSTR + lk];
#pragma unroll
        for (int mi = 0; mi < 2; ++mi)
#pragma unroll
            for (int ni = 0; ni < 4; ++ni)
                acc[mi][ni] = __builtin_amdgcn_mfma_f32_16x16x32_bf16(
                    af[mi], bf[ni], acc[mi][ni], 0, 0, 0);
    }
    __syncthreads();   // frag reads done before sOff overwrites sA/sB

    // ---- phase 3a: epilogue -> sOff (swizzled [32][256] bf16) ----
#pragma unroll
    for (int mi = 0; mi < 2; ++mi)
#pragma unroll
        for (int ni = 0; ni < 4; ++ni) {
            int col = w * 64 + ni * 16 + lrow;
            float b = bso[col];
            int qrow = mi * 16 + g * 4;
#pragma unroll
            for (int r = 0; r < 4; ++r) {
                int row = qrow + r;
                *(uint16_t*)(smem + row * 512 + ((col * 2) ^ ((row & 7) << 4))) =
                    f2bf(acc[mi][ni][r] + b);
            }
        }

    // ---- phase 3b: fp32 scores (thread = (h2, ql)) + in-thread softmax ----
    // two half-d passes to keep register peak low
    float sc[16];
#pragma unroll
    for (int kk = 0; kk < 16; ++kk) sc[kk] = 0.f;
#pragma unroll
    for (int half = 0; half < 2; ++half) {
        const float4_* qp = (const float4_*)(q + (size_t)qa * 256 + h2 * 32 + half * 16);
        float4_ qv[4];
#pragma unroll
        for (int j = 0; j < 4; ++j) qv[j] = qp[j];
#pragma unroll
        for (int kk = 0; kk < 16; ++kk) {
            const float4_* kp = (const float4_*)(key + kk * 256 + h2 * 32 + half * 16);
            float a = 0.f;
#pragma unroll
            for (int j = 0; j < 4; ++j) {
                float4_ kv = kp[j];
                a += qv[j].x * kv.x + qv[j].y * kv.y + qv[j].z * kv.z + qv[j].w * kv.w;
            }
            sc[kk] += a;
        }
    }
    {
        float m = sc[0];
#pragma unroll
        for (int kk = 1; kk < 16; ++kk) m = fmaxf(m, sc[kk]);
        float s = 0.f;
#pragma unroll
        for (int kk = 0; kk < 16; ++kk) { sc[kk] = __expf(sc[kk] - m); s += sc[kk]; }
        float inv = 1.f / s;
#pragma unroll
        for (int kk = 0; kk < 16; ++kk) sc[kk] *= inv;
    }
    __syncthreads();

    // ---- phase 4a: sample into register bins; offsets loaded per-level ----
    float4_ r01 = *(const float4_*)(refp + (size_t)qa * 8);
    float4_ r23 = *(const float4_*)(refp + (size_t)qa * 8 + 4);
    float rx[4] = {r01.x, r01.z, r23.x, r23.z};
    float ry[4] = {r01.y, r01.w, r23.y, r23.w};

    float ws[14];
#pragma unroll
    for (int j = 0; j < 14; ++j) ws[j] = 0.f;

    // norm by (W,H)[pp]: W={2,2,3,2}, H={1,2,2,1}; sample grid by lev.
    // Level lev's 4 points live in one short8 at sOff col h2*64+lev*16.
#define SAMPLE_PT(J, PP, GH, GW, ST, NW, NH)                                  \
    {                                                                         \
        float ox = bf2f((uint16_t)ovl.s[2 * (J)]);                            \
        float oy = bf2f((uint16_t)ovl.s[2 * (J) + 1]);                        \
        float x = (rx[PP] + ox * (NW)) * (float)(GW)-0.5f;                    \
        float y = (ry[PP] + oy * (NH)) * (float)(GH)-0.5f;                    \
        scatter<GH, GW, ST>(ws, sc[4 * LEV + (J)], x, y);                     \
    }
    {
        union OvU { short8 v; short s[8]; } ovl;
#define LEV 0
        ovl.v = *(const short8*)(smem + ql * 512 + ((h2 * 64 + LEV * 16) ^ ((ql & 7) << 4)));
        SAMPLE_PT(0, 0, 1, 2, 0, 0.5f, 1.0f)
        SAMPLE_PT(1, 1, 1, 2, 0, 0.5f, 0.5f)
        SAMPLE_PT(2, 2, 1, 2, 0, (1.f / 3.f), 0.5f)
        SAMPLE_PT(3, 3, 1, 2, 0, 0.5f, 1.0f)
#undef LEV
#define LEV 1
        ovl.v = *(const short8*)(smem + ql * 512 + ((h2 * 64 + LEV * 16) ^ ((ql & 7) << 4)));
        SAMPLE_PT(0, 0, 2, 2, 2, 0.5f, 1.0f)
        SAMPLE_PT(1, 1, 2, 2, 2, 0.5f, 0.5f)
        SAMPLE_PT(2, 2, 2, 2, 2, (1.f / 3.f), 0.5f)
        SAMPLE_PT(3, 3, 2, 2, 2, 0.5f, 1.0f)
#undef LEV
#define LEV 2
        ovl.v = *(const short8*)(smem + ql * 512 + ((h2 * 64 + LEV * 16) ^ ((ql & 7) << 4)));
        SAMPLE_PT(0, 0, 2, 3, 6, 0.5f, 1.0f)
        SAMPLE_PT(1, 1, 2, 3, 6, 0.5f, 0.5f)
        SAMPLE_PT(2, 2, 2, 3, 6, (1.f / 3.f), 0.5f)
        SAMPLE_PT(3, 3, 2, 3, 6, 0.5f, 1.0f)
#undef LEV
#define LEV 3
        ovl.v = *(const short8*)(smem + ql * 512 + ((h2 * 64 + LEV * 16) ^ ((ql & 7) << 4)));
        SAMPLE_PT(0, 0, 1, 2, 12, 0.5f, 1.0f)
        SAMPLE_PT(1, 1, 1, 2, 12, 0.5f, 0.5f)
        SAMPLE_PT(2, 2, 1, 2, 12, (1.f / 3.f), 0.5f)
        SAMPLE_PT(3, 3, 1, 2, 12, 0.5f, 1.0f)
#undef LEV
    }
#undef SAMPLE_PT

    __syncthreads();   // everyone done reading sOff

    // ---- phase 4b: pack ws -> wsFrag [256][48B] (row = t = h2*32+ql) ----
    {
        union PkU { uint32_t u[8]; short8 v2[2]; } pk;
#pragma unroll
        for (int j = 0; j < 7; ++j)
            pk.u[j] = (uint32_t)f2bf(ws[2 * j]) | ((uint32_t)f2bf(ws[2 * j + 1]) << 16);
        pk.u[7] = 0;
        *(short8*)(smem + t * 48)      = pk.v2[0];
        *(short8*)(smem + t * 48 + 16) = pk.v2[1];
    }
    __syncthreads();

    // ---- phase 5: out = wsum @ value; wave w serves heads {2w, 2w+1} ----
    {
        union ZU { uint32_t u[4]; short8 v; } az;
        az.u[0] = 0; az.u[1] = 0; az.u[2] = 0; az.u[3] = 0;
#pragma unroll
        for (int hh = 0; hh < 2; ++hh) {
            int h = 2 * w + hh;
            union VbU { short8 v; uint16_t u[8]; } vb[2];
#pragma unroll
            for (int nt = 0; nt < 2; ++nt) {
                if (g < 2) {
                    int col = h * 32 + nt * 16 + lrow;
#pragma unroll
                    for (int j = 0; j < 8; ++j)
                        vb[nt].u[j] = f2bf(value[(g * 8 + j) * 256 + col]);
                } else {
                    vb[nt].v = az.v;
                }
            }
            float4_ acc2[2][2];
#pragma unroll
            for (int i = 0; i < 2; ++i)
#pragma unroll
                for (int j = 0; j < 2; ++j) acc2[i][j] = (float4_)0.f;
#pragma unroll
            for (int mt = 0; mt < 2; ++mt) {
                short8 af = (g < 2)
                    ? *(const short8*)(smem + (h * 32 + mt * 16 + lrow) * 48 + g * 16)
                    : az.v;
#pragma unroll
                for (int nt = 0; nt < 2; ++nt)
                    acc2[mt][nt] = __builtin_amdgcn_mfma_f32_16x16x32_bf16(
                        af, vb[nt].v, acc2[mt][nt], 0, 0, 0);
            }
#pragma unroll
            for (int mt = 0; mt < 2; ++mt)
#pragma unroll
                for (int nt = 0; nt < 2; ++nt)
#pragma unroll
                    for (int r = 0; r < 4; ++r)
                        out[(size_t)(qbase + mt * 16 + g * 4 + r) * 256
                            + h * 32 + nt * 16 + lrow] = acc2[mt][nt][r];
        }
    }
}

extern "C" void kernel_launch(void* const* d_in, const int* in_sizes, int n_in,
                              void* d_out, int out_size, void* d_ws, size_t ws_size,
                              hipStream_t stream) {
    (void)in_sizes; (void)n_in; (void)out_size; (void)ws_size;
    const float* query = (const float*)d_in[0];
    const float* key   = (const float*)d_in[1];
    const float* value = (const float*)d_in[2];
    const float* refp  = (const float*)d_in[3];
    const float* Wso   = (const float*)d_in[5];
    const float* bso   = (const float*)d_in[6];
    uint16_t* WTb = (uint16_t*)d_ws;

    hipLaunchKernelGGL(k_transpose, dim3(256), dim3(256), 0, stream, Wso, WTb);
    hipLaunchKernelGGL(k_fused, dim3(1250), dim3(256), 0, stream,
                       query, key, value, refp, WTb, bso, (float*)d_out);
}